// Round 3
// baseline (357.460 us; speedup 1.0000x reference)
//
#include <hip/hip_runtime.h>
#include <stdint.h>

// Bloom filter, 2^27 bits = 16 MiB bitset, 7 hashes.
// Hash positions for value v are 7 CONSECUTIVE bits starting at
//   p = ((uint32)v * 2654435761u) & (2^27 - 1)
// (only the low 27 bits of the int64 hash survive the mask, so the whole
//  hash collapses to a 32-bit multiply; seeds 0..6 are consecutive bits).
// Harness dtypes: integer inputs -> int32; bool output -> int32 (0/1).

#define NUM_BITS_LOG2 27
#define NUM_BITS (1u << NUM_BITS_LOG2)
#define BIT_MASK (NUM_BITS - 1u)
#define NUM_WORDS (NUM_BITS >> 6)      // 2^21 uint64 words = 16 MiB
#define WORD_MASK (NUM_WORDS - 1u)
#define PRIME 2654435761u

__global__ void zero_bits_kernel(ulonglong2* __restrict__ bits, int n2) {
    int i = blockIdx.x * blockDim.x + threadIdx.x;
    if (i < n2) {
        bits[i] = ulonglong2{0ull, 0ull};
    }
}

__global__ void insert_kernel(const int* __restrict__ vals, int n,
                              unsigned long long* __restrict__ bits) {
    int i = blockIdx.x * blockDim.x + threadIdx.x;
    if (i >= n) return;
    uint32_t v = (uint32_t)vals[i];
    uint32_t p = (v * PRIME) & BIT_MASK;
    uint32_t w = p >> 6;
    uint32_t b = p & 63u;
    atomicOr(bits + w, 0x7Full << b);             // bits >=64 shift out naturally
    if (b > 57u) {                                // 7-bit window straddles words
        atomicOr(bits + ((w + 1u) & WORD_MASK), 0x7Full >> (64u - b));
    }
}

__global__ void query_kernel(const int* __restrict__ vals, int n,
                             const unsigned long long* __restrict__ bits,
                             int* __restrict__ out) {
    int i = blockIdx.x * blockDim.x + threadIdx.x;
    if (i >= n) return;
    uint32_t v = (uint32_t)vals[i];
    uint32_t p = (v * PRIME) & BIT_MASK;
    uint32_t w = p >> 6;
    uint32_t b = p & 63u;
    unsigned long long lo = bits[w];
    unsigned long long window;
    if (b <= 57u) {
        window = lo >> b;
    } else {
        unsigned long long hi = bits[(w + 1u) & WORD_MASK];
        window = (lo >> b) | (hi << (64u - b));
    }
    out[i] = ((window & 0x7Full) == 0x7Full) ? 1 : 0;
}

extern "C" void kernel_launch(void* const* d_in, const int* in_sizes, int n_in,
                              void* d_out, int out_size, void* d_ws, size_t ws_size,
                              hipStream_t stream) {
    const int* add_values   = (const int*)d_in[0];
    const int* query_values = (const int*)d_in[1];
    const int n_add   = in_sizes[0];   // 4,000,000
    const int n_query = in_sizes[1];   // 8,000,000
    int* out = (int*)d_out;

    unsigned long long* bits = (unsigned long long*)d_ws;   // 16 MiB bitset

    // 1) zero the bitset (ws is poisoned to 0xAA before every call)
    {
        const int n2 = NUM_WORDS / 2;                       // ulonglong2 count
        const int block = 256;
        zero_bits_kernel<<<(n2 + block - 1) / block, block, 0, stream>>>(
            (ulonglong2*)bits, n2);
    }
    // 2) insert
    {
        const int block = 256;
        insert_kernel<<<(n_add + block - 1) / block, block, 0, stream>>>(
            add_values, n_add, bits);
    }
    // 3) query
    {
        const int block = 256;
        query_kernel<<<(n_query + block - 1) / block, block, 0, stream>>>(
            query_values, n_query, bits, out);
    }
}